// Round 6
// baseline (517.129 us; speedup 1.0000x reference)
//
#include <hip/hip_runtime.h>

#define NN 262144
#define KK 1024
#define DD 64
#define DECAY 0.99f
#define ONE_MINUS_DECAY 0.01f
#define EPSF 1e-5f
#define COMMIT 0.25f

// padded bf16 codebook planes: 144B per code row (72 bf16, 64 used + 8 pad)
#define ROWB 144
// chunk = 64 codes, DOUBLE-BUFFERED: 2 x 18432B = 36864B LDS -> 4 blocks/CU
#define CHUNK_CODES 64
#define PLANE_BYTES (CHUNK_CODES * ROWB)       // 9216
#define CHUNK_BYTES (PLANE_BYTES * 2)          // 18432
#define NCHUNK (KK / CHUNK_CODES)              // 16

typedef __bf16 bf16x8 __attribute__((ext_vector_type(8)));
typedef unsigned short ushort8 __attribute__((ext_vector_type(8)));
typedef float float4v __attribute__((ext_vector_type(4)));

__device__ inline unsigned short bf16rne(float f) {
    unsigned int u = __float_as_uint(f);
    u += 0x7fffu + ((u >> 16) & 1u);
    return (unsigned short)(u >> 16);
}

// async global->LDS, 16B per lane; LDS dest must be linear in lane order
__device__ inline void glds16(const void* g, void* l) {
    __builtin_amdgcn_global_load_lds(
        (const __attribute__((address_space(1))) unsigned int*)g,
        (__attribute__((address_space(3))) unsigned int*)l, 16, 0, 0);
}

// --- fused: split codebook into chunked padded bf16 hi/lo planes + 0.5||c||^2
//     + zero-init of counts/dw/loss (replaces hipMemsetAsync dispatch)
__global__ __launch_bounds__(256) void k_prep(const float* __restrict__ cb,
                                              unsigned char* __restrict__ cbhl,
                                              float* __restrict__ csq_half,
                                              int* __restrict__ counts,
                                              float* __restrict__ dw,
                                              float* __restrict__ loss_acc) {
    int e = blockIdx.x * 256 + threadIdx.x;      // 0..65535 == KK*DD
    dw[e] = 0.f;
    if (e < KK) counts[e] = 0;
    if (e == 0) loss_acc[0] = 0.f;
    int k = e >> 6, d = e & 63;
    int c = k >> 6, kl = k & 63;
    float f = cb[e];
    unsigned short h = bf16rne(f);
    float hf = __uint_as_float((unsigned int)h << 16);
    unsigned short l = bf16rne(f - hf);
    unsigned char* base = cbhl + (size_t)c * CHUNK_BYTES;
    *(unsigned short*)(base + kl * ROWB + d * 2) = h;
    *(unsigned short*)(base + PLANE_BYTES + kl * ROWB + d * 2) = l;
    float s = f * f;
#pragma unroll
    for (int off = 32; off > 0; off >>= 1) s += __shfl_down(s, off);
    if (d == 0) csq_half[k] = 0.5f * s;
}

// --- assignment core: split-bf16 MFMA, packed-uint top-2 ONLY ---------------
// wave = 32 rows (2 m-tiles x 16), round-2 structure. Epilogue split into
// k_refine (round-5); ends by writing packed (k1 | k2<<10) per row.
// MFMA chain split 4+2 into two accumulators per m-tile (4-way ILP).
// Bias (0.5||x||^2 + 1) folded into the MFMA acc init so acc =
// 0.5||x-c||^2 + 1 >= 1 directly: raw float bits monotone, low 10 bits
// carry the code; top-2 via and_or + min + v_med3_u32 (3 VALU per dp).
__global__ __launch_bounds__(256, 4) void k_assign(
    const float* __restrict__ x,
    const unsigned char* __restrict__ cbhl, const float* __restrict__ csq_half,
    int* __restrict__ kkpack)
{
    __shared__ __align__(16) unsigned char ldsbuf[2][CHUNK_BYTES];

    const int tid  = threadIdx.x;
    const int lane = tid & 63;
    const int wave = tid >> 6;
    const int col  = lane & 15;
    const int quad = lane >> 4;
    const int rowbase = blockIdx.x * 128 + wave * 32;

    // ---- issue stage of chunk 0 first: hides under the x-fragment prologue
    {
        const unsigned char* src = cbhl;
#pragma unroll
        for (int i = 0; i < 4; ++i) {
            int off = (i * 256 + tid) * 16;
            glds16(src + off, &ldsbuf[0][off]);
        }
        if (tid < 128) {
            int off = 16384 + tid * 16;
            glds16(src + off, &ldsbuf[0][off]);
        }
    }

    // ---- negated split-bf16 A fragments (2 m-tiles x 2 k-halves) + bias
    bf16x8 nah[2][2], nal[2][2];
    float xsq1[8];      // [mt*4+r] = 0.5*||x_row||^2 + 1, row = mt*16+quad*4+r
    {
        float xsqm[2];
#pragma unroll
        for (int mt = 0; mt < 2; ++mt) {
            const float* xb = x + (size_t)(rowbase + mt * 16 + col) * DD + quad * 8;
            float s = 0.f;
#pragma unroll
            for (int kh = 0; kh < 2; ++kh) {
                float4 f0 = *(const float4*)(xb + kh * 32);
                float4 f1 = *(const float4*)(xb + kh * 32 + 4);
                s += f0.x * f0.x + f0.y * f0.y + f0.z * f0.z + f0.w * f0.w;
                s += f1.x * f1.x + f1.y * f1.y + f1.z * f1.z + f1.w * f1.w;
                float fv[8] = {f0.x, f0.y, f0.z, f0.w, f1.x, f1.y, f1.z, f1.w};
                ushort8 uh, ul;
#pragma unroll
                for (int j = 0; j < 8; ++j) {
                    float nf = -fv[j];
                    unsigned short h = bf16rne(nf);
                    float hf = __uint_as_float((unsigned int)h << 16);
                    uh[j] = h;
                    ul[j] = bf16rne(nf - hf);
                }
                nah[mt][kh] = __builtin_bit_cast(bf16x8, uh);
                nal[mt][kh] = __builtin_bit_cast(bf16x8, ul);
            }
            s += __shfl_xor(s, 16);
            s += __shfl_xor(s, 32);          // full row norm^2 at all quads
            xsqm[mt] = s;
        }
#pragma unroll
        for (int mt = 0; mt < 2; ++mt)
#pragma unroll
            for (int r = 0; r < 4; ++r)
                xsq1[mt * 4 + r] = 0.5f * __shfl(xsqm[mt], quad * 4 + r) + 1.0f;
    }

    // ---- packed top-2 (value-bits | code) per 8 rows/lane
    unsigned int best[8], sec[8];
#pragma unroll
    for (int j = 0; j < 8; ++j) { best[j] = 0xFFFFFFFFu; sec[j] = 0xFFFFFFFFu; }

    // chunk 0 staged + x fragments done -> buffer 0 visible to all
    asm volatile("s_waitcnt vmcnt(0) lgkmcnt(0)" ::: "memory");
    __builtin_amdgcn_s_barrier();

    for (int chunk = 0; chunk < NCHUNK; ++chunk) {
        const unsigned char* cbuf = ldsbuf[chunk & 1];
        if (chunk + 1 < NCHUNK) {               // issue next-chunk stage
            unsigned char* nbuf = ldsbuf[(chunk + 1) & 1];
            const unsigned char* src = cbhl + (size_t)(chunk + 1) * CHUNK_BYTES;
#pragma unroll
            for (int i = 0; i < 4; ++i) {
                int off = (i * 256 + tid) * 16;
                glds16(src + off, nbuf + off);
            }
            if (tid < 128) {
                int off = 16384 + tid * 16;
                glds16(src + off, nbuf + off);
            }
        }

        float csqv[4];                        // per-chunk csq preload (L1-hit)
#pragma unroll
        for (int ct = 0; ct < 4; ++ct)
            csqv[ct] = csq_half[chunk * CHUNK_CODES + ct * 16 + col];

#pragma unroll
        for (int ct = 0; ct < CHUNK_CODES / 16; ++ct) {        // 4 code-tiles
            const int code_local = ct * 16 + col;
            const unsigned int codeCol = chunk * CHUNK_CODES + code_local;
            const unsigned char* bp = cbuf + code_local * ROWB + quad * 16;
            bf16x8 bh0 = __builtin_bit_cast(bf16x8, *(const uint4*)(bp));
            bf16x8 bh1 = __builtin_bit_cast(bf16x8, *(const uint4*)(bp + 64));
            bf16x8 bl0 = __builtin_bit_cast(bf16x8, *(const uint4*)(bp + PLANE_BYTES));
            bf16x8 bl1 = __builtin_bit_cast(bf16x8, *(const uint4*)(bp + PLANE_BYTES + 64));
            float csq = csqv[ct];

#pragma unroll
            for (int mt = 0; mt < 2; ++mt) {
                // two accumulators: 4-deep + 2-deep chains (4-way ILP with mt)
                float4v a = {csq + xsq1[mt * 4 + 0], csq + xsq1[mt * 4 + 1],
                             csq + xsq1[mt * 4 + 2], csq + xsq1[mt * 4 + 3]};
                float4v b = {0.f, 0.f, 0.f, 0.f};
                __builtin_amdgcn_s_setprio(1);
                a = __builtin_amdgcn_mfma_f32_16x16x32_bf16(nah[mt][0], bh0, a, 0, 0, 0);
                a = __builtin_amdgcn_mfma_f32_16x16x32_bf16(nah[mt][1], bh1, a, 0, 0, 0);
                b = __builtin_amdgcn_mfma_f32_16x16x32_bf16(nah[mt][0], bl0, b, 0, 0, 0);
                b = __builtin_amdgcn_mfma_f32_16x16x32_bf16(nah[mt][1], bl1, b, 0, 0, 0);
                a = __builtin_amdgcn_mfma_f32_16x16x32_bf16(nal[mt][0], bh0, a, 0, 0, 0);
                a = __builtin_amdgcn_mfma_f32_16x16x32_bf16(nal[mt][1], bh1, a, 0, 0, 0);
                __builtin_amdgcn_s_setprio(0);
#pragma unroll
                for (int r = 0; r < 4; ++r) {
                    float av = a[r] + b[r];
                    // av >= 1 -> bits monotone; 4 VALU per dp total
                    unsigned int u = (__float_as_uint(av) & 0xFFFFFC00u) | codeCol;
                    unsigned int j = mt * 4 + r;
                    unsigned int s2;
                    // sec' = min(sec, max(best_old, u)) == med3(best_old, u, sec)
                    // (invariant sec >= best)
                    asm("v_med3_u32 %0, %1, %2, %3"
                        : "=v"(s2) : "v"(best[j]), "v"(u), "v"(sec[j]));
                    sec[j] = s2;
                    best[j] = best[j] < u ? best[j] : u;
                }
            }
        }

        // wait own ds_reads landed + next-chunk DMA complete, then sync
        asm volatile("s_waitcnt vmcnt(0) lgkmcnt(0)" ::: "memory");
        __builtin_amdgcn_s_barrier();
    }

    // ---- merge top-2 across the 16 col-lanes (packed: pure min/max)
#pragma unroll
    for (int m = 1; m <= 8; m <<= 1) {
#pragma unroll
        for (int j = 0; j < 8; ++j) {
            unsigned int ob = __shfl_xor(best[j], m, 16);
            unsigned int os = __shfl_xor(sec[j],  m, 16);
            unsigned int hi = best[j] > ob ? best[j] : ob;
            best[j] = best[j] < ob ? best[j] : ob;
            unsigned int s2 = sec[j] < os ? sec[j] : os;
            sec[j] = s2 < hi ? s2 : hi;
        }
    }

    // ---- write packed (k1 | k2<<10) per row; k_refine re-ranks exactly
    if (col == 0) {
#pragma unroll
        for (int j = 0; j < 8; ++j) {
            int row_local = (j >> 2) * 16 + quad * 4 + (j & 3);
            kkpack[rowbase + row_local] =
                (int)((best[j] & 1023u) | ((sec[j] & 1023u) << 10));
        }
    }
}

// --- exact fp32 refinement: COALESCED 16-lanes-per-row layout ---------------
// Round-5 failure: 2-lanes-per-row made every load a 64-cache-line gather
// (lane stride 128B), latency-bound at 123us / VALUBusy 2.8%. Now thread
// e owns float4-slot (e&15) of row (e>>4): 16 lanes = one row contiguous,
// wave = 4 consecutive rows = 1024B contiguous -> fully coalesced loads and
// stores. Winner row needs no re-gather: quant = pick1 ? c1 : c2.
__global__ __launch_bounds__(256) void k_refine(
    const float* __restrict__ x, const float* __restrict__ cb,
    const float* __restrict__ csq_half, int* __restrict__ idx_io,
    float* __restrict__ quant, int* __restrict__ counts,
    float* __restrict__ loss_acc)
{
    __shared__ float werr[4];
    const int tid  = threadIdx.x;
    const int lane = tid & 63;
    const int d16  = lane & 15;           // float4 slot within row
    const int e    = blockIdx.x * 256 + tid;
    const int row  = e >> 4;

    unsigned int kp = (unsigned int)idx_io[row];   // 16 lanes same addr: bcast
    int k1 = (int)(kp & 1023u), k2 = (int)((kp >> 10) & 1023u);

    float4 x4 = *(const float4*)(x + (size_t)row * DD + d16 * 4);
    float4 c1 = *(const float4*)(cb + (size_t)k1 * DD + d16 * 4);
    float4 c2 = *(const float4*)(cb + (size_t)k2 * DD + d16 * 4);

    float p1 = x4.x * c1.x + x4.y * c1.y + x4.z * c1.z + x4.w * c1.w;
    float p2 = x4.x * c2.x + x4.y * c2.y + x4.z * c2.z + x4.w * c2.w;
#pragma unroll
    for (int off = 1; off < 16; off <<= 1) {
        p1 += __shfl_xor(p1, off, 16);
        p2 += __shfl_xor(p2, off, 16);
    }
    float d1 = csq_half[k1] - p1;
    float d2 = csq_half[k2] - p2;
    bool pick1 = (d1 < d2) || (d1 == d2 && k1 < k2);
    int w = pick1 ? k1 : k2;
    float4 q = pick1 ? c1 : c2;

    *(float4*)(quant + (size_t)row * DD + d16 * 4) = q;

    float ex = q.x - x4.x, ey = q.y - x4.y, ez = q.z - x4.z, ew = q.w - x4.w;
    float err = ex * ex + ey * ey + ez * ez + ew * ew;
#pragma unroll
    for (int off = 32; off > 0; off >>= 1) err += __shfl_down(err, off);
    if (lane == 0) werr[tid >> 6] = err;
    __syncthreads();
    if (tid == 0)
        atomicAdd(loss_acc, werr[0] + werr[1] + werr[2] + werr[3]);

    if (d16 == 0) {
        idx_io[row] = w;
        atomicAdd(&counts[w], 1);
    }
}

// --- single block: EMA cluster size, n-reduce, smoothed, scan, loss ---------
__global__ __launch_bounds__(1024) void k_mid(
    const int* __restrict__ counts, const float* __restrict__ ema_cs,
    const float* __restrict__ loss_acc,
    float* __restrict__ new_cs, float* __restrict__ loss_out,
    float* __restrict__ smoothed_inv, int* __restrict__ offsets,
    int* __restrict__ cursor)
{
    int t = threadIdx.x; int lane = t & 63; int w = t >> 6;
    int cnt = counts[t];
    float ncs = DECAY * ema_cs[t] + ONE_MINUS_DECAY * (float)cnt;

    __shared__ float wsumf[16];
    __shared__ int wsumi[16];
    __shared__ float ntot_s;

    float s = ncs;
#pragma unroll
    for (int off = 32; off > 0; off >>= 1) s += __shfl_down(s, off);
    if (lane == 0) wsumf[w] = s;

    int v = cnt;
#pragma unroll
    for (int off = 1; off < 64; off <<= 1) {
        int u = __shfl_up(v, off);
        if (lane >= off) v += u;
    }
    if (lane == 63) wsumi[w] = v;
    __syncthreads();
    if (t == 0) {
        float tt = 0.f;
        for (int i = 0; i < 16; ++i) tt += wsumf[i];
        ntot_s = tt;
    }
    if (w == 0 && lane < 16) {
        int u = wsumi[lane]; int vv = u;
#pragma unroll
        for (int off = 1; off < 16; off <<= 1) {
            int p = __shfl_up(vv, off, 16);
            if ((lane & 15) >= off) vv += p;
        }
        wsumi[lane] = vv - u;
    }
    __syncthreads();
    float n = ntot_s;

    float sm = (ncs + EPSF) / (n + (float)KK * EPSF) * n;
    new_cs[t] = ncs;
    smoothed_inv[t] = 1.0f / sm;

    int excl = wsumi[w] + v - cnt;
    offsets[t] = excl;
    cursor[t] = excl;

    if (t == 0) loss_out[0] = COMMIT * loss_acc[0] / (float)(NN * DD);
}

// --- scatter rows into per-code segments: one int2 {row, code} per position -
__global__ __launch_bounds__(256) void k_scatter(
    int* __restrict__ idx_inout, int* __restrict__ cursor,
    int2* __restrict__ pairs)
{
    int i = blockIdx.x * 256 + threadIdx.x;
    int k = idx_inout[i];
    int pos = atomicAdd(&cursor[k], 1);
    pairs[pos] = make_int2(i, k);
    ((float*)idx_inout)[i] = (float)k;   // own-element read happened above
}

// --- balanced segment sum: each wave 64 sorted rows, shfl-broadcast keys ----
// batched 8-wide: 8 independent gathers issued per group so HBM/L2 latency
// is exposed once per 8 rows instead of per row (the old fully-serial loop)
__global__ __launch_bounds__(256) void k_segsum(
    const float* __restrict__ x, const int2* __restrict__ pairs,
    float* __restrict__ dw)
{
    int w = blockIdx.x * 4 + (threadIdx.x >> 6);   // 4096 waves total
    int lane = threadIdx.x & 63;
    int base = w * 64;
    int2 mine = pairs[base + lane];                // coalesced 512B per wave
    float acc = 0.f;
    int cur = __shfl(mine.y, 0);
    for (int rb = 0; rb < 64; rb += 8) {
        float v[8];
        int codes[8];
#pragma unroll
        for (int j = 0; j < 8; ++j) {
            int row  = __shfl(mine.x, rb + j);
            codes[j] = __shfl(mine.y, rb + j);
            v[j] = x[(size_t)row * DD + lane];     // 256B coalesced gather
        }
#pragma unroll
        for (int j = 0; j < 8; ++j) {
            if (codes[j] != cur) {                 // wave-uniform, rare
                atomicAdd(&dw[cur * DD + lane], acc);
                acc = 0.f; cur = codes[j];
            }
            acc += v[j];
        }
    }
    atomicAdd(&dw[cur * DD + lane], acc);
}

// --- EMA weight update + codebook normalize --------------------------------
__global__ __launch_bounds__(256) void k_final(
    const float* __restrict__ dw, const float* __restrict__ ema_w,
    const float* __restrict__ smoothed_inv,
    float* __restrict__ new_ema_w, float* __restrict__ new_cb)
{
    int i = blockIdx.x * 256 + threadIdx.x;
    int k = i >> 6;
    float nw = DECAY * ema_w[i] + ONE_MINUS_DECAY * dw[i];
    new_ema_w[i] = nw;
    new_cb[i] = nw * smoothed_inv[k];
}

extern "C" void kernel_launch(void* const* d_in, const int* in_sizes, int n_in,
                              void* d_out, int out_size, void* d_ws, size_t ws_size,
                              hipStream_t stream)
{
    const float* x      = (const float*)d_in[0];
    const float* cb     = (const float*)d_in[1];
    const float* ema_cs = (const float*)d_in[2];
    const float* ema_w  = (const float*)d_in[3];

    float* out      = (float*)d_out;
    float* quant    = out;                                   // [N*D]
    float* loss_out = out + (size_t)NN * DD;                 // [1]
    int*   idx_reg  = (int*)(out + (size_t)NN * DD + 1);     // [N] (float slot)
    float* new_cb   = out + (size_t)NN * DD + 1 + NN;        // [K*D]
    float* new_cs   = new_cb + (size_t)KK * DD;              // [K]
    float* new_emaw = new_cs + KK;                           // [K*D]

    char* ws = (char*)d_ws;
    float* loss_acc     = (float*)(ws + 0);                  // 256 B
    int*   counts       = (int*)(ws + 256);                  // 4 KB
    float* dw           = (float*)(ws + 4352);               // 256 KB
    int*   offsets      = (int*)(ws + 266496);               // 4 KB
    int*   cursor       = (int*)(ws + 270592);               // 4 KB
    float* csq_half     = (float*)(ws + 274688);             // 4 KB
    float* smoothed_inv = (float*)(ws + 278784);             // 4 KB
    unsigned char* cbhl = (unsigned char*)(ws + 282880);     // 288 KB
    int2*  pairs        = (int2*)(ws + 577792);              // 2 MB

    k_prep   <<<KK * DD / 256, 256, 0, stream>>>(cb, cbhl, csq_half,
                                                 counts, dw, loss_acc);
    k_assign <<<NN / 128, 256, 0, stream>>>(x, cbhl, csq_half, idx_reg);
    k_refine <<<NN * (DD / 4) / 256, 256, 0, stream>>>(x, cb, csq_half,
                                                       idx_reg, quant,
                                                       counts, loss_acc);
    k_mid    <<<1, 1024, 0, stream>>>(counts, ema_cs, loss_acc, new_cs,
                                      loss_out, smoothed_inv, offsets, cursor);
    k_scatter<<<NN / 256, 256, 0, stream>>>(idx_reg, cursor, pairs);
    k_segsum <<<NN / 256, 256, 0, stream>>>(x, pairs, dw);
    k_final  <<<KK * DD / 256, 256, 0, stream>>>(dw, ema_w, smoothed_inv,
                                                 new_emaw, new_cb);
}

// Round 7
// 455.919 us; speedup vs baseline: 1.1343x; 1.1343x over previous
//
#include <hip/hip_runtime.h>

#define NN 262144
#define KK 1024
#define DD 64
#define DECAY 0.99f
#define ONE_MINUS_DECAY 0.01f
#define EPSF 1e-5f
#define COMMIT 0.25f

// padded bf16 codebook planes: 144B per code row (72 bf16, 64 used + 8 pad)
#define ROWB 144
// chunk = 64 codes, DOUBLE-BUFFERED: 2 x 18432B = 36864B LDS -> 4 blocks/CU
#define CHUNK_CODES 64
#define PLANE_BYTES (CHUNK_CODES * ROWB)       // 9216
#define CHUNK_BYTES (PLANE_BYTES * 2)          // 18432
#define NCHUNK (KK / CHUNK_CODES)              // 16
#define RBLK 16384                              // k_refine blocks (= NN*16/256)

typedef __bf16 bf16x8 __attribute__((ext_vector_type(8)));
typedef unsigned short ushort8 __attribute__((ext_vector_type(8)));
typedef float float4v __attribute__((ext_vector_type(4)));

__device__ inline unsigned short bf16rne(float f) {
    unsigned int u = __float_as_uint(f);
    u += 0x7fffu + ((u >> 16) & 1u);
    return (unsigned short)(u >> 16);
}

// async global->LDS, 16B per lane; LDS dest must be linear in lane order
__device__ inline void glds16(const void* g, void* l) {
    __builtin_amdgcn_global_load_lds(
        (const __attribute__((address_space(1))) unsigned int*)g,
        (__attribute__((address_space(3))) unsigned int*)l, 16, 0, 0);
}

// --- fused: split codebook into chunked padded bf16 hi/lo planes + 0.5||c||^2
//     + zero-init of counts/dw (replaces hipMemsetAsync dispatch)
__global__ __launch_bounds__(256) void k_prep(const float* __restrict__ cb,
                                              unsigned char* __restrict__ cbhl,
                                              float* __restrict__ csq_half,
                                              int* __restrict__ counts,
                                              float* __restrict__ dw) {
    int e = blockIdx.x * 256 + threadIdx.x;      // 0..65535 == KK*DD
    dw[e] = 0.f;
    if (e < KK) counts[e] = 0;
    int k = e >> 6, d = e & 63;
    int c = k >> 6, kl = k & 63;
    float f = cb[e];
    unsigned short h = bf16rne(f);
    float hf = __uint_as_float((unsigned int)h << 16);
    unsigned short l = bf16rne(f - hf);
    unsigned char* base = cbhl + (size_t)c * CHUNK_BYTES;
    *(unsigned short*)(base + kl * ROWB + d * 2) = h;
    *(unsigned short*)(base + PLANE_BYTES + kl * ROWB + d * 2) = l;
    float s = f * f;
#pragma unroll
    for (int off = 32; off > 0; off >>= 1) s += __shfl_down(s, off);
    if (d == 0) csq_half[k] = 0.5f * s;
}

// --- assignment core: split-bf16 MFMA, packed-uint top-2 ONLY ---------------
// wave = 32 rows (2 m-tiles x 16), round-2 structure. Epilogue split into
// k_refine; ends by writing packed (k1 | k2<<10) per row.
// MFMA chain split 4+2 into two accumulators per m-tile (4-way ILP).
// Bias (0.5||x||^2 + 1) folded into the MFMA acc init so acc =
// 0.5||x-c||^2 + 1 >= 1 directly: raw float bits monotone, low 10 bits
// carry the code; top-2 via and_or + min + v_med3_u32 (3 VALU per dp).
__global__ __launch_bounds__(256, 4) void k_assign(
    const float* __restrict__ x,
    const unsigned char* __restrict__ cbhl, const float* __restrict__ csq_half,
    int* __restrict__ kkpack)
{
    __shared__ __align__(16) unsigned char ldsbuf[2][CHUNK_BYTES];

    const int tid  = threadIdx.x;
    const int lane = tid & 63;
    const int wave = tid >> 6;
    const int col  = lane & 15;
    const int quad = lane >> 4;
    const int rowbase = blockIdx.x * 128 + wave * 32;

    // ---- issue stage of chunk 0 first: hides under the x-fragment prologue
    {
        const unsigned char* src = cbhl;
#pragma unroll
        for (int i = 0; i < 4; ++i) {
            int off = (i * 256 + tid) * 16;
            glds16(src + off, &ldsbuf[0][off]);
        }
        if (tid < 128) {
            int off = 16384 + tid * 16;
            glds16(src + off, &ldsbuf[0][off]);
        }
    }

    // ---- negated split-bf16 A fragments (2 m-tiles x 2 k-halves) + bias
    bf16x8 nah[2][2], nal[2][2];
    float xsq1[8];      // [mt*4+r] = 0.5*||x_row||^2 + 1, row = mt*16+quad*4+r
    {
        float xsqm[2];
#pragma unroll
        for (int mt = 0; mt < 2; ++mt) {
            const float* xb = x + (size_t)(rowbase + mt * 16 + col) * DD + quad * 8;
            float s = 0.f;
#pragma unroll
            for (int kh = 0; kh < 2; ++kh) {
                float4 f0 = *(const float4*)(xb + kh * 32);
                float4 f1 = *(const float4*)(xb + kh * 32 + 4);
                s += f0.x * f0.x + f0.y * f0.y + f0.z * f0.z + f0.w * f0.w;
                s += f1.x * f1.x + f1.y * f1.y + f1.z * f1.z + f1.w * f1.w;
                float fv[8] = {f0.x, f0.y, f0.z, f0.w, f1.x, f1.y, f1.z, f1.w};
                ushort8 uh, ul;
#pragma unroll
                for (int j = 0; j < 8; ++j) {
                    float nf = -fv[j];
                    unsigned short h = bf16rne(nf);
                    float hf = __uint_as_float((unsigned int)h << 16);
                    uh[j] = h;
                    ul[j] = bf16rne(nf - hf);
                }
                nah[mt][kh] = __builtin_bit_cast(bf16x8, uh);
                nal[mt][kh] = __builtin_bit_cast(bf16x8, ul);
            }
            s += __shfl_xor(s, 16);
            s += __shfl_xor(s, 32);          // full row norm^2 at all quads
            xsqm[mt] = s;
        }
#pragma unroll
        for (int mt = 0; mt < 2; ++mt)
#pragma unroll
            for (int r = 0; r < 4; ++r)
                xsq1[mt * 4 + r] = 0.5f * __shfl(xsqm[mt], quad * 4 + r) + 1.0f;
    }

    // ---- packed top-2 (value-bits | code) per 8 rows/lane
    unsigned int best[8], sec[8];
#pragma unroll
    for (int j = 0; j < 8; ++j) { best[j] = 0xFFFFFFFFu; sec[j] = 0xFFFFFFFFu; }

    // chunk 0 staged + x fragments done -> buffer 0 visible to all
    asm volatile("s_waitcnt vmcnt(0) lgkmcnt(0)" ::: "memory");
    __builtin_amdgcn_s_barrier();

    for (int chunk = 0; chunk < NCHUNK; ++chunk) {
        const unsigned char* cbuf = ldsbuf[chunk & 1];
        if (chunk + 1 < NCHUNK) {               // issue next-chunk stage
            unsigned char* nbuf = ldsbuf[(chunk + 1) & 1];
            const unsigned char* src = cbhl + (size_t)(chunk + 1) * CHUNK_BYTES;
#pragma unroll
            for (int i = 0; i < 4; ++i) {
                int off = (i * 256 + tid) * 16;
                glds16(src + off, nbuf + off);
            }
            if (tid < 128) {
                int off = 16384 + tid * 16;
                glds16(src + off, nbuf + off);
            }
        }

        float csqv[4];                        // per-chunk csq preload (L1-hit)
#pragma unroll
        for (int ct = 0; ct < 4; ++ct)
            csqv[ct] = csq_half[chunk * CHUNK_CODES + ct * 16 + col];

#pragma unroll
        for (int ct = 0; ct < CHUNK_CODES / 16; ++ct) {        // 4 code-tiles
            const int code_local = ct * 16 + col;
            const unsigned int codeCol = chunk * CHUNK_CODES + code_local;
            const unsigned char* bp = cbuf + code_local * ROWB + quad * 16;
            bf16x8 bh0 = __builtin_bit_cast(bf16x8, *(const uint4*)(bp));
            bf16x8 bh1 = __builtin_bit_cast(bf16x8, *(const uint4*)(bp + 64));
            bf16x8 bl0 = __builtin_bit_cast(bf16x8, *(const uint4*)(bp + PLANE_BYTES));
            bf16x8 bl1 = __builtin_bit_cast(bf16x8, *(const uint4*)(bp + PLANE_BYTES + 64));
            float csq = csqv[ct];

#pragma unroll
            for (int mt = 0; mt < 2; ++mt) {
                // two accumulators: 4-deep + 2-deep chains (4-way ILP with mt)
                float4v a = {csq + xsq1[mt * 4 + 0], csq + xsq1[mt * 4 + 1],
                             csq + xsq1[mt * 4 + 2], csq + xsq1[mt * 4 + 3]};
                float4v b = {0.f, 0.f, 0.f, 0.f};
                __builtin_amdgcn_s_setprio(1);
                a = __builtin_amdgcn_mfma_f32_16x16x32_bf16(nah[mt][0], bh0, a, 0, 0, 0);
                a = __builtin_amdgcn_mfma_f32_16x16x32_bf16(nah[mt][1], bh1, a, 0, 0, 0);
                b = __builtin_amdgcn_mfma_f32_16x16x32_bf16(nah[mt][0], bl0, b, 0, 0, 0);
                b = __builtin_amdgcn_mfma_f32_16x16x32_bf16(nah[mt][1], bl1, b, 0, 0, 0);
                a = __builtin_amdgcn_mfma_f32_16x16x32_bf16(nal[mt][0], bh0, a, 0, 0, 0);
                a = __builtin_amdgcn_mfma_f32_16x16x32_bf16(nal[mt][1], bh1, a, 0, 0, 0);
                __builtin_amdgcn_s_setprio(0);
#pragma unroll
                for (int r = 0; r < 4; ++r) {
                    float av = a[r] + b[r];
                    // av >= 1 -> bits monotone; 4 VALU per dp total
                    unsigned int u = (__float_as_uint(av) & 0xFFFFFC00u) | codeCol;
                    unsigned int j = mt * 4 + r;
                    unsigned int s2;
                    // sec' = min(sec, max(best_old, u)) == med3(best_old, u, sec)
                    // (invariant sec >= best)
                    asm("v_med3_u32 %0, %1, %2, %3"
                        : "=v"(s2) : "v"(best[j]), "v"(u), "v"(sec[j]));
                    sec[j] = s2;
                    best[j] = best[j] < u ? best[j] : u;
                }
            }
        }

        // wait own ds_reads landed + next-chunk DMA complete, then sync
        asm volatile("s_waitcnt vmcnt(0) lgkmcnt(0)" ::: "memory");
        __builtin_amdgcn_s_barrier();
    }

    // ---- merge top-2 across the 16 col-lanes (packed: pure min/max)
#pragma unroll
    for (int m = 1; m <= 8; m <<= 1) {
#pragma unroll
        for (int j = 0; j < 8; ++j) {
            unsigned int ob = __shfl_xor(best[j], m, 16);
            unsigned int os = __shfl_xor(sec[j],  m, 16);
            unsigned int hi = best[j] > ob ? best[j] : ob;
            best[j] = best[j] < ob ? best[j] : ob;
            unsigned int s2 = sec[j] < os ? sec[j] : os;
            sec[j] = s2 < hi ? s2 : hi;
        }
    }

    // ---- write packed (k1 | k2<<10) per row; k_refine re-ranks exactly
    if (col == 0) {
#pragma unroll
        for (int j = 0; j < 8; ++j) {
            int row_local = (j >> 2) * 16 + quad * 4 + (j & 3);
            kkpack[rowbase + row_local] =
                (int)((best[j] & 1023u) | ((sec[j] & 1023u) << 10));
        }
    }
}

// --- exact fp32 refinement: coalesced 16-lanes-per-row, NO single-addr atomic
// Round-6 counters (VALUBusy 5.5%, identical 214.401us durations, occupancy
// 65%) exposed the real serializer: 16384 atomicAdds to the single loss_acc
// address (~13ns each, cross-XCD coherence serial floor). Loss now goes to
// loss_parts[blockIdx.x] via a plain store; k_mid reduces the array.
__global__ __launch_bounds__(256) void k_refine(
    const float* __restrict__ x, const float* __restrict__ cb,
    const float* __restrict__ csq_half, int* __restrict__ idx_io,
    float* __restrict__ quant, int* __restrict__ counts,
    float* __restrict__ loss_parts)
{
    __shared__ float werr[4];
    const int tid  = threadIdx.x;
    const int lane = tid & 63;
    const int d16  = lane & 15;           // float4 slot within row
    const int e    = blockIdx.x * 256 + tid;
    const int row  = e >> 4;

    unsigned int kp = (unsigned int)idx_io[row];   // 16 lanes same addr: bcast
    int k1 = (int)(kp & 1023u), k2 = (int)((kp >> 10) & 1023u);

    float4 x4 = *(const float4*)(x + (size_t)row * DD + d16 * 4);
    float4 c1 = *(const float4*)(cb + (size_t)k1 * DD + d16 * 4);
    float4 c2 = *(const float4*)(cb + (size_t)k2 * DD + d16 * 4);

    float p1 = x4.x * c1.x + x4.y * c1.y + x4.z * c1.z + x4.w * c1.w;
    float p2 = x4.x * c2.x + x4.y * c2.y + x4.z * c2.z + x4.w * c2.w;
#pragma unroll
    for (int off = 1; off < 16; off <<= 1) {
        p1 += __shfl_xor(p1, off, 16);
        p2 += __shfl_xor(p2, off, 16);
    }
    float d1 = csq_half[k1] - p1;
    float d2 = csq_half[k2] - p2;
    bool pick1 = (d1 < d2) || (d1 == d2 && k1 < k2);
    int w = pick1 ? k1 : k2;
    float4 q = pick1 ? c1 : c2;

    *(float4*)(quant + (size_t)row * DD + d16 * 4) = q;

    float ex = q.x - x4.x, ey = q.y - x4.y, ez = q.z - x4.z, ew = q.w - x4.w;
    float err = ex * ex + ey * ey + ez * ez + ew * ew;
#pragma unroll
    for (int off = 32; off > 0; off >>= 1) err += __shfl_down(err, off);
    if (lane == 0) werr[tid >> 6] = err;
    __syncthreads();
    if (tid == 0)
        loss_parts[blockIdx.x] = werr[0] + werr[1] + werr[2] + werr[3];

    if (d16 == 0) {
        idx_io[row] = w;
        atomicAdd(&counts[w], 1);   // spread over 1024 addrs: parallel channels
    }
}

// --- single block: EMA cluster size, n-reduce, smoothed, scan, loss-reduce --
__global__ __launch_bounds__(1024) void k_mid(
    const int* __restrict__ counts, const float* __restrict__ ema_cs,
    const float* __restrict__ loss_parts,
    float* __restrict__ new_cs, float* __restrict__ loss_out,
    float* __restrict__ smoothed_inv, int* __restrict__ offsets,
    int* __restrict__ cursor)
{
    int t = threadIdx.x; int lane = t & 63; int w = t >> 6;
    int cnt = counts[t];
    float ncs = DECAY * ema_cs[t] + ONE_MINUS_DECAY * (float)cnt;

    __shared__ float wsumf[16];
    __shared__ int wsumi[16];
    __shared__ float wlp[16];
    __shared__ float ntot_s;

    // loss_parts reduce: 16384 = 1024 x 16 coalesced
    float lp = 0.f;
#pragma unroll
    for (int i = 0; i < RBLK / 1024; ++i) lp += loss_parts[t + i * 1024];
#pragma unroll
    for (int off = 32; off > 0; off >>= 1) lp += __shfl_down(lp, off);
    if (lane == 0) wlp[w] = lp;

    float s = ncs;
#pragma unroll
    for (int off = 32; off > 0; off >>= 1) s += __shfl_down(s, off);
    if (lane == 0) wsumf[w] = s;

    int v = cnt;
#pragma unroll
    for (int off = 1; off < 64; off <<= 1) {
        int u = __shfl_up(v, off);
        if (lane >= off) v += u;
    }
    if (lane == 63) wsumi[w] = v;
    __syncthreads();
    if (t == 0) {
        float tt = 0.f, lt = 0.f;
        for (int i = 0; i < 16; ++i) { tt += wsumf[i]; lt += wlp[i]; }
        ntot_s = tt;
        loss_out[0] = COMMIT * lt / (float)(NN * DD);
    }
    if (w == 0 && lane < 16) {
        int u = wsumi[lane]; int vv = u;
#pragma unroll
        for (int off = 1; off < 16; off <<= 1) {
            int p = __shfl_up(vv, off, 16);
            if ((lane & 15) >= off) vv += p;
        }
        wsumi[lane] = vv - u;
    }
    __syncthreads();
    float n = ntot_s;

    float sm = (ncs + EPSF) / (n + (float)KK * EPSF) * n;
    new_cs[t] = ncs;
    smoothed_inv[t] = 1.0f / sm;

    int excl = wsumi[w] + v - cnt;
    offsets[t] = excl;
    cursor[t] = excl;
}

// --- scatter rows into per-code segments: one int2 {row, code} per position -
__global__ __launch_bounds__(256) void k_scatter(
    int* __restrict__ idx_inout, int* __restrict__ cursor,
    int2* __restrict__ pairs)
{
    int i = blockIdx.x * 256 + threadIdx.x;
    int k = idx_inout[i];
    int pos = atomicAdd(&cursor[k], 1);
    pairs[pos] = make_int2(i, k);
    ((float*)idx_inout)[i] = (float)k;   // own-element read happened above
}

// --- balanced segment sum: each wave 64 sorted rows, shfl-broadcast keys ----
// batched 8-wide: 8 independent gathers issued per group so HBM/L2 latency
// is exposed once per 8 rows instead of per row (the old fully-serial loop)
__global__ __launch_bounds__(256) void k_segsum(
    const float* __restrict__ x, const int2* __restrict__ pairs,
    float* __restrict__ dw)
{
    int w = blockIdx.x * 4 + (threadIdx.x >> 6);   // 4096 waves total
    int lane = threadIdx.x & 63;
    int base = w * 64;
    int2 mine = pairs[base + lane];                // coalesced 512B per wave
    float acc = 0.f;
    int cur = __shfl(mine.y, 0);
    for (int rb = 0; rb < 64; rb += 8) {
        float v[8];
        int codes[8];
#pragma unroll
        for (int j = 0; j < 8; ++j) {
            int row  = __shfl(mine.x, rb + j);
            codes[j] = __shfl(mine.y, rb + j);
            v[j] = x[(size_t)row * DD + lane];     // 256B coalesced gather
        }
#pragma unroll
        for (int j = 0; j < 8; ++j) {
            if (codes[j] != cur) {                 // wave-uniform, rare
                atomicAdd(&dw[cur * DD + lane], acc);
                acc = 0.f; cur = codes[j];
            }
            acc += v[j];
        }
    }
    atomicAdd(&dw[cur * DD + lane], acc);
}

// --- EMA weight update + codebook normalize --------------------------------
__global__ __launch_bounds__(256) void k_final(
    const float* __restrict__ dw, const float* __restrict__ ema_w,
    const float* __restrict__ smoothed_inv,
    float* __restrict__ new_ema_w, float* __restrict__ new_cb)
{
    int i = blockIdx.x * 256 + threadIdx.x;
    int k = i >> 6;
    float nw = DECAY * ema_w[i] + ONE_MINUS_DECAY * dw[i];
    new_ema_w[i] = nw;
    new_cb[i] = nw * smoothed_inv[k];
}

extern "C" void kernel_launch(void* const* d_in, const int* in_sizes, int n_in,
                              void* d_out, int out_size, void* d_ws, size_t ws_size,
                              hipStream_t stream)
{
    const float* x      = (const float*)d_in[0];
    const float* cb     = (const float*)d_in[1];
    const float* ema_cs = (const float*)d_in[2];
    const float* ema_w  = (const float*)d_in[3];

    float* out      = (float*)d_out;
    float* quant    = out;                                   // [N*D]
    float* loss_out = out + (size_t)NN * DD;                 // [1]
    int*   idx_reg  = (int*)(out + (size_t)NN * DD + 1);     // [N] (float slot)
    float* new_cb   = out + (size_t)NN * DD + 1 + NN;        // [K*D]
    float* new_cs   = new_cb + (size_t)KK * DD;              // [K]
    float* new_emaw = new_cs + KK;                           // [K*D]

    char* ws = (char*)d_ws;
    int*   counts       = (int*)(ws + 256);                  // 4 KB
    float* dw           = (float*)(ws + 4352);               // 256 KB
    int*   offsets      = (int*)(ws + 266496);               // 4 KB
    int*   cursor       = (int*)(ws + 270592);               // 4 KB
    float* csq_half     = (float*)(ws + 274688);             // 4 KB
    float* smoothed_inv = (float*)(ws + 278784);             // 4 KB
    unsigned char* cbhl = (unsigned char*)(ws + 282880);     // 288 KB
    int2*  pairs        = (int2*)(ws + 577792);              // 2 MB
    // loss_parts reuses the pairs region (written by k_refine, reduced by
    // k_mid, only afterwards overwritten by k_scatter)
    float* loss_parts   = (float*)(ws + 577792);             // 64 KB

    k_prep   <<<KK * DD / 256, 256, 0, stream>>>(cb, cbhl, csq_half,
                                                 counts, dw);
    k_assign <<<NN / 128, 256, 0, stream>>>(x, cbhl, csq_half, idx_reg);
    k_refine <<<RBLK, 256, 0, stream>>>(x, cb, csq_half, idx_reg, quant,
                                        counts, loss_parts);
    k_mid    <<<1, 1024, 0, stream>>>(counts, ema_cs, loss_parts, new_cs,
                                      loss_out, smoothed_inv, offsets, cursor);
    k_scatter<<<NN / 256, 256, 0, stream>>>(idx_reg, cursor, pairs);
    k_segsum <<<NN / 256, 256, 0, stream>>>(x, pairs, dw);
    k_final  <<<KK * DD / 256, 256, 0, stream>>>(dw, ema_w, smoothed_inv,
                                                 new_emaw, new_cb);
}

// Round 8
// 262.459 us; speedup vs baseline: 1.9703x; 1.7371x over previous
//
#include <hip/hip_runtime.h>

#define NN 262144
#define KK 1024
#define DD 64
#define DECAY 0.99f
#define ONE_MINUS_DECAY 0.01f
#define EPSF 1e-5f
#define COMMIT 0.25f

// padded bf16 codebook planes: 144B per code row (72 bf16, 64 used + 8 pad)
#define ROWB 144
// chunk = 64 codes, DOUBLE-BUFFERED: 2 x 18432B = 36864B LDS -> 4 blocks/CU
#define CHUNK_CODES 64
#define PLANE_BYTES (CHUNK_CODES * ROWB)       // 9216
#define CHUNK_BYTES (PLANE_BYTES * 2)          // 18432
#define NCHUNK (KK / CHUNK_CODES)              // 16
#define RBLK 16384                              // k_refine blocks (= NN*16/256)
#define CBLK 64                                 // count/scatter blocks
#define ROWS_PER_CBLK (NN / CBLK)               // 4096

typedef __bf16 bf16x8 __attribute__((ext_vector_type(8)));
typedef unsigned short ushort8 __attribute__((ext_vector_type(8)));
typedef float float4v __attribute__((ext_vector_type(4)));

__device__ inline unsigned short bf16rne(float f) {
    unsigned int u = __float_as_uint(f);
    u += 0x7fffu + ((u >> 16) & 1u);
    return (unsigned short)(u >> 16);
}

// async global->LDS, 16B per lane; LDS dest must be linear in lane order
__device__ inline void glds16(const void* g, void* l) {
    __builtin_amdgcn_global_load_lds(
        (const __attribute__((address_space(1))) unsigned int*)g,
        (__attribute__((address_space(3))) unsigned int*)l, 16, 0, 0);
}

// --- fused: split codebook into chunked padded bf16 hi/lo planes + 0.5||c||^2
//     + zero-init of dw
__global__ __launch_bounds__(256) void k_prep(const float* __restrict__ cb,
                                              unsigned char* __restrict__ cbhl,
                                              float* __restrict__ csq_half,
                                              float* __restrict__ dw) {
    int e = blockIdx.x * 256 + threadIdx.x;      // 0..65535 == KK*DD
    dw[e] = 0.f;
    int k = e >> 6, d = e & 63;
    int c = k >> 6, kl = k & 63;
    float f = cb[e];
    unsigned short h = bf16rne(f);
    float hf = __uint_as_float((unsigned int)h << 16);
    unsigned short l = bf16rne(f - hf);
    unsigned char* base = cbhl + (size_t)c * CHUNK_BYTES;
    *(unsigned short*)(base + kl * ROWB + d * 2) = h;
    *(unsigned short*)(base + PLANE_BYTES + kl * ROWB + d * 2) = l;
    float s = f * f;
#pragma unroll
    for (int off = 32; off > 0; off >>= 1) s += __shfl_down(s, off);
    if (d == 0) csq_half[k] = 0.5f * s;
}

// --- assignment core: split-bf16 MFMA, packed-uint top-2 ONLY ---------------
// wave = 32 rows (2 m-tiles x 16), round-2 structure. Writes packed
// (k1 | k2<<10) per row; k_refine re-ranks exactly in fp32.
__global__ __launch_bounds__(256, 4) void k_assign(
    const float* __restrict__ x,
    const unsigned char* __restrict__ cbhl, const float* __restrict__ csq_half,
    int* __restrict__ kkpack)
{
    __shared__ __align__(16) unsigned char ldsbuf[2][CHUNK_BYTES];

    const int tid  = threadIdx.x;
    const int lane = tid & 63;
    const int wave = tid >> 6;
    const int col  = lane & 15;
    const int quad = lane >> 4;
    const int rowbase = blockIdx.x * 128 + wave * 32;

    // ---- issue stage of chunk 0 first: hides under the x-fragment prologue
    {
        const unsigned char* src = cbhl;
#pragma unroll
        for (int i = 0; i < 4; ++i) {
            int off = (i * 256 + tid) * 16;
            glds16(src + off, &ldsbuf[0][off]);
        }
        if (tid < 128) {
            int off = 16384 + tid * 16;
            glds16(src + off, &ldsbuf[0][off]);
        }
    }

    // ---- negated split-bf16 A fragments (2 m-tiles x 2 k-halves) + bias
    bf16x8 nah[2][2], nal[2][2];
    float xsq1[8];      // [mt*4+r] = 0.5*||x_row||^2 + 1, row = mt*16+quad*4+r
    {
        float xsqm[2];
#pragma unroll
        for (int mt = 0; mt < 2; ++mt) {
            const float* xb = x + (size_t)(rowbase + mt * 16 + col) * DD + quad * 8;
            float s = 0.f;
#pragma unroll
            for (int kh = 0; kh < 2; ++kh) {
                float4 f0 = *(const float4*)(xb + kh * 32);
                float4 f1 = *(const float4*)(xb + kh * 32 + 4);
                s += f0.x * f0.x + f0.y * f0.y + f0.z * f0.z + f0.w * f0.w;
                s += f1.x * f1.x + f1.y * f1.y + f1.z * f1.z + f1.w * f1.w;
                float fv[8] = {f0.x, f0.y, f0.z, f0.w, f1.x, f1.y, f1.z, f1.w};
                ushort8 uh, ul;
#pragma unroll
                for (int j = 0; j < 8; ++j) {
                    float nf = -fv[j];
                    unsigned short h = bf16rne(nf);
                    float hf = __uint_as_float((unsigned int)h << 16);
                    uh[j] = h;
                    ul[j] = bf16rne(nf - hf);
                }
                nah[mt][kh] = __builtin_bit_cast(bf16x8, uh);
                nal[mt][kh] = __builtin_bit_cast(bf16x8, ul);
            }
            s += __shfl_xor(s, 16);
            s += __shfl_xor(s, 32);          // full row norm^2 at all quads
            xsqm[mt] = s;
        }
#pragma unroll
        for (int mt = 0; mt < 2; ++mt)
#pragma unroll
            for (int r = 0; r < 4; ++r)
                xsq1[mt * 4 + r] = 0.5f * __shfl(xsqm[mt], quad * 4 + r) + 1.0f;
    }

    // ---- packed top-2 (value-bits | code) per 8 rows/lane
    unsigned int best[8], sec[8];
#pragma unroll
    for (int j = 0; j < 8; ++j) { best[j] = 0xFFFFFFFFu; sec[j] = 0xFFFFFFFFu; }

    // chunk 0 staged + x fragments done -> buffer 0 visible to all
    asm volatile("s_waitcnt vmcnt(0) lgkmcnt(0)" ::: "memory");
    __builtin_amdgcn_s_barrier();

    for (int chunk = 0; chunk < NCHUNK; ++chunk) {
        const unsigned char* cbuf = ldsbuf[chunk & 1];
        if (chunk + 1 < NCHUNK) {               // issue next-chunk stage
            unsigned char* nbuf = ldsbuf[(chunk + 1) & 1];
            const unsigned char* src = cbhl + (size_t)(chunk + 1) * CHUNK_BYTES;
#pragma unroll
            for (int i = 0; i < 4; ++i) {
                int off = (i * 256 + tid) * 16;
                glds16(src + off, nbuf + off);
            }
            if (tid < 128) {
                int off = 16384 + tid * 16;
                glds16(src + off, nbuf + off);
            }
        }

        float csqv[4];                        // per-chunk csq preload (L1-hit)
#pragma unroll
        for (int ct = 0; ct < 4; ++ct)
            csqv[ct] = csq_half[chunk * CHUNK_CODES + ct * 16 + col];

#pragma unroll
        for (int ct = 0; ct < CHUNK_CODES / 16; ++ct) {        // 4 code-tiles
            const int code_local = ct * 16 + col;
            const unsigned int codeCol = chunk * CHUNK_CODES + code_local;
            const unsigned char* bp = cbuf + code_local * ROWB + quad * 16;
            bf16x8 bh0 = __builtin_bit_cast(bf16x8, *(const uint4*)(bp));
            bf16x8 bh1 = __builtin_bit_cast(bf16x8, *(const uint4*)(bp + 64));
            bf16x8 bl0 = __builtin_bit_cast(bf16x8, *(const uint4*)(bp + PLANE_BYTES));
            bf16x8 bl1 = __builtin_bit_cast(bf16x8, *(const uint4*)(bp + PLANE_BYTES + 64));
            float csq = csqv[ct];

#pragma unroll
            for (int mt = 0; mt < 2; ++mt) {
                // two accumulators: 4-deep + 2-deep chains (4-way ILP with mt)
                float4v a = {csq + xsq1[mt * 4 + 0], csq + xsq1[mt * 4 + 1],
                             csq + xsq1[mt * 4 + 2], csq + xsq1[mt * 4 + 3]};
                float4v b = {0.f, 0.f, 0.f, 0.f};
                __builtin_amdgcn_s_setprio(1);
                a = __builtin_amdgcn_mfma_f32_16x16x32_bf16(nah[mt][0], bh0, a, 0, 0, 0);
                a = __builtin_amdgcn_mfma_f32_16x16x32_bf16(nah[mt][1], bh1, a, 0, 0, 0);
                b = __builtin_amdgcn_mfma_f32_16x16x32_bf16(nah[mt][0], bl0, b, 0, 0, 0);
                b = __builtin_amdgcn_mfma_f32_16x16x32_bf16(nah[mt][1], bl1, b, 0, 0, 0);
                a = __builtin_amdgcn_mfma_f32_16x16x32_bf16(nal[mt][0], bh0, a, 0, 0, 0);
                a = __builtin_amdgcn_mfma_f32_16x16x32_bf16(nal[mt][1], bh1, a, 0, 0, 0);
                __builtin_amdgcn_s_setprio(0);
#pragma unroll
                for (int r = 0; r < 4; ++r) {
                    float av = a[r] + b[r];
                    // av >= 1 -> bits monotone; 4 VALU per dp total
                    unsigned int u = (__float_as_uint(av) & 0xFFFFFC00u) | codeCol;
                    unsigned int j = mt * 4 + r;
                    unsigned int s2;
                    // sec' = min(sec, max(best_old, u)) == med3(best_old, u, sec)
                    // (invariant sec >= best)
                    asm("v_med3_u32 %0, %1, %2, %3"
                        : "=v"(s2) : "v"(best[j]), "v"(u), "v"(sec[j]));
                    sec[j] = s2;
                    best[j] = best[j] < u ? best[j] : u;
                }
            }
        }

        // wait own ds_reads landed + next-chunk DMA complete, then sync
        asm volatile("s_waitcnt vmcnt(0) lgkmcnt(0)" ::: "memory");
        __builtin_amdgcn_s_barrier();
    }

    // ---- merge top-2 across the 16 col-lanes (packed: pure min/max)
#pragma unroll
    for (int m = 1; m <= 8; m <<= 1) {
#pragma unroll
        for (int j = 0; j < 8; ++j) {
            unsigned int ob = __shfl_xor(best[j], m, 16);
            unsigned int os = __shfl_xor(sec[j],  m, 16);
            unsigned int hi = best[j] > ob ? best[j] : ob;
            best[j] = best[j] < ob ? best[j] : ob;
            unsigned int s2 = sec[j] < os ? sec[j] : os;
            sec[j] = s2 < hi ? s2 : hi;
        }
    }

    // ---- write packed (k1 | k2<<10) per row; k_refine re-ranks exactly
    if (col == 0) {
#pragma unroll
        for (int j = 0; j < 8; ++j) {
            int row_local = (j >> 2) * 16 + quad * 4 + (j & 3);
            kkpack[rowbase + row_local] =
                (int)((best[j] & 1023u) | ((sec[j] & 1023u) << 10));
        }
    }
}

// --- exact fp32 refinement: coalesced, ZERO global atomics ------------------
// Round-7 counters (identical 151.52us durations, VALUBusy 5.5%, 511 GB/s)
// fingered the 262K counts atomicAdds over 64 cache lines (~37ns/line-op
// cross-XCD ping-pong = 151us floor). Counts now come from a separate LDS-
// histogram kernel; k_refine is pure streaming.
__global__ __launch_bounds__(256) void k_refine(
    const float* __restrict__ x, const float* __restrict__ cb,
    const float* __restrict__ csq_half, int* __restrict__ idx_io,
    float* __restrict__ quant, float* __restrict__ loss_parts)
{
    __shared__ float werr[4];
    const int tid  = threadIdx.x;
    const int lane = tid & 63;
    const int d16  = lane & 15;           // float4 slot within row
    const int e    = blockIdx.x * 256 + tid;
    const int row  = e >> 4;

    unsigned int kp = (unsigned int)idx_io[row];   // 16 lanes same addr: bcast
    int k1 = (int)(kp & 1023u), k2 = (int)((kp >> 10) & 1023u);

    float4 x4 = *(const float4*)(x + (size_t)row * DD + d16 * 4);
    float4 c1 = *(const float4*)(cb + (size_t)k1 * DD + d16 * 4);
    float4 c2 = *(const float4*)(cb + (size_t)k2 * DD + d16 * 4);

    float p1 = x4.x * c1.x + x4.y * c1.y + x4.z * c1.z + x4.w * c1.w;
    float p2 = x4.x * c2.x + x4.y * c2.y + x4.z * c2.z + x4.w * c2.w;
#pragma unroll
    for (int off = 1; off < 16; off <<= 1) {
        p1 += __shfl_xor(p1, off, 16);
        p2 += __shfl_xor(p2, off, 16);
    }
    float d1 = csq_half[k1] - p1;
    float d2 = csq_half[k2] - p2;
    bool pick1 = (d1 < d2) || (d1 == d2 && k1 < k2);
    int w = pick1 ? k1 : k2;
    float4 q = pick1 ? c1 : c2;

    *(float4*)(quant + (size_t)row * DD + d16 * 4) = q;

    float ex = q.x - x4.x, ey = q.y - x4.y, ez = q.z - x4.z, ew = q.w - x4.w;
    float err = ex * ex + ey * ey + ez * ez + ew * ew;
#pragma unroll
    for (int off = 32; off > 0; off >>= 1) err += __shfl_down(err, off);
    if (lane == 0) werr[tid >> 6] = err;
    __syncthreads();
    if (tid == 0)
        loss_parts[blockIdx.x] = werr[0] + werr[1] + werr[2] + werr[3];

    if (d16 == 0) idx_io[row] = w;       // plain store, no atomic
}

// --- per-block LDS histogram: 64 blocks x 4096 rows, plain-store partials ---
__global__ __launch_bounds__(256) void k_count(
    const int* __restrict__ idx, int* __restrict__ counts_parts)
{
    __shared__ int hist[KK];
    const int tid = threadIdx.x;
    const int b   = blockIdx.x;
#pragma unroll
    for (int i = 0; i < KK / 256; ++i) hist[tid + i * 256] = 0;
    __syncthreads();
    const int base = b * ROWS_PER_CBLK;
    for (int i = tid; i < ROWS_PER_CBLK; i += 256)
        atomicAdd(&hist[idx[base + i]], 1);          // LDS atomic (ds_add)
    __syncthreads();
#pragma unroll
    for (int i = 0; i < KK / 256; ++i)
        counts_parts[b * KK + tid + i * 256] = hist[tid + i * 256];
}

// --- single block: counts-reduce, EMA, smoothed, scan, loss, scatter bases --
// Transforms counts_parts IN PLACE into per-block scatter base offsets.
__global__ __launch_bounds__(1024) void k_mid(
    int* __restrict__ counts_parts, const float* __restrict__ ema_cs,
    const float* __restrict__ loss_parts,
    float* __restrict__ new_cs, float* __restrict__ loss_out,
    float* __restrict__ smoothed_inv)
{
    int t = threadIdx.x; int lane = t & 63; int w = t >> 6;

    __shared__ float wsumf[16];
    __shared__ int wsumi[16];
    __shared__ float wlp[16];
    __shared__ float ntot_s;

    // loss_parts reduce: 16384 = 1024 x 16 coalesced
    float lp = 0.f;
#pragma unroll
    for (int i = 0; i < RBLK / 1024; ++i) lp += loss_parts[t + i * 1024];
#pragma unroll
    for (int off = 32; off > 0; off >>= 1) lp += __shfl_down(lp, off);
    if (lane == 0) wlp[w] = lp;

    // counts[t] = sum over 64 per-block partials (coalesced per iteration)
    int cnt = 0;
    for (int b = 0; b < CBLK; ++b) cnt += counts_parts[b * KK + t];
    float ncs = DECAY * ema_cs[t] + ONE_MINUS_DECAY * (float)cnt;

    float s = ncs;
#pragma unroll
    for (int off = 32; off > 0; off >>= 1) s += __shfl_down(s, off);
    if (lane == 0) wsumf[w] = s;

    int v = cnt;
#pragma unroll
    for (int off = 1; off < 64; off <<= 1) {
        int u = __shfl_up(v, off);
        if (lane >= off) v += u;
    }
    if (lane == 63) wsumi[w] = v;
    __syncthreads();
    if (t == 0) {
        float tt = 0.f, lt = 0.f;
        for (int i = 0; i < 16; ++i) { tt += wsumf[i]; lt += wlp[i]; }
        ntot_s = tt;
        loss_out[0] = COMMIT * lt / (float)(NN * DD);
    }
    if (w == 0 && lane < 16) {
        int u = wsumi[lane]; int vv = u;
#pragma unroll
        for (int off = 1; off < 16; off <<= 1) {
            int p = __shfl_up(vv, off, 16);
            if ((lane & 15) >= off) vv += p;
        }
        wsumi[lane] = vv - u;
    }
    __syncthreads();
    float n = ntot_s;

    float sm = (ncs + EPSF) / (n + (float)KK * EPSF) * n;
    new_cs[t] = ncs;
    smoothed_inv[t] = 1.0f / sm;

    // exclusive global offset of code t, then in-place transform of
    // counts_parts[b][t] -> scatter base for block b (column t is exclusive
    // to thread t: no races)
    int run = wsumi[w] + v - cnt;
    for (int b = 0; b < CBLK; ++b) {
        int c = counts_parts[b * KK + t];
        counts_parts[b * KK + t] = run;
        run += c;
    }
}

// --- scatter via LDS cursors seeded from per-block bases: no global atomics -
__global__ __launch_bounds__(256) void k_scatter(
    int* __restrict__ idx_inout, const int* __restrict__ base_parts,
    int2* __restrict__ pairs)
{
    __shared__ int cur[KK];
    const int tid = threadIdx.x;
    const int b   = blockIdx.x;
#pragma unroll
    for (int i = 0; i < KK / 256; ++i)
        cur[tid + i * 256] = base_parts[b * KK + tid + i * 256];
    __syncthreads();
    const int base = b * ROWS_PER_CBLK;
    for (int i = tid; i < ROWS_PER_CBLK; i += 256) {
        int k = idx_inout[base + i];
        int pos = atomicAdd(&cur[k], 1);             // LDS atomic
        pairs[pos] = make_int2(base + i, k);
        ((float*)idx_inout)[base + i] = (float)k;    // final float output
    }
}

// --- balanced segment sum: each wave 64 sorted rows, shfl-broadcast keys ----
// batched 8-wide: 8 independent gathers issued per group so HBM/L2 latency
// is exposed once per 8 rows instead of per row
__global__ __launch_bounds__(256) void k_segsum(
    const float* __restrict__ x, const int2* __restrict__ pairs,
    float* __restrict__ dw)
{
    int w = blockIdx.x * 4 + (threadIdx.x >> 6);   // 4096 waves total
    int lane = threadIdx.x & 63;
    int base = w * 64;
    int2 mine = pairs[base + lane];                // coalesced 512B per wave
    float acc = 0.f;
    int cur = __shfl(mine.y, 0);
    for (int rb = 0; rb < 64; rb += 8) {
        float v[8];
        int codes[8];
#pragma unroll
        for (int j = 0; j < 8; ++j) {
            int row  = __shfl(mine.x, rb + j);
            codes[j] = __shfl(mine.y, rb + j);
            v[j] = x[(size_t)row * DD + lane];     // 256B coalesced gather
        }
#pragma unroll
        for (int j = 0; j < 8; ++j) {
            if (codes[j] != cur) {                 // wave-uniform, rare
                atomicAdd(&dw[cur * DD + lane], acc);
                acc = 0.f; cur = codes[j];
            }
            acc += v[j];
        }
    }
    atomicAdd(&dw[cur * DD + lane], acc);
}

// --- EMA weight update + codebook normalize --------------------------------
__global__ __launch_bounds__(256) void k_final(
    const float* __restrict__ dw, const float* __restrict__ ema_w,
    const float* __restrict__ smoothed_inv,
    float* __restrict__ new_ema_w, float* __restrict__ new_cb)
{
    int i = blockIdx.x * 256 + threadIdx.x;
    int k = i >> 6;
    float nw = DECAY * ema_w[i] + ONE_MINUS_DECAY * dw[i];
    new_ema_w[i] = nw;
    new_cb[i] = nw * smoothed_inv[k];
}

extern "C" void kernel_launch(void* const* d_in, const int* in_sizes, int n_in,
                              void* d_out, int out_size, void* d_ws, size_t ws_size,
                              hipStream_t stream)
{
    const float* x      = (const float*)d_in[0];
    const float* cb     = (const float*)d_in[1];
    const float* ema_cs = (const float*)d_in[2];
    const float* ema_w  = (const float*)d_in[3];

    float* out      = (float*)d_out;
    float* quant    = out;                                   // [N*D]
    float* loss_out = out + (size_t)NN * DD;                 // [1]
    int*   idx_reg  = (int*)(out + (size_t)NN * DD + 1);     // [N] (float slot)
    float* new_cb   = out + (size_t)NN * DD + 1 + NN;        // [K*D]
    float* new_cs   = new_cb + (size_t)KK * DD;              // [K]
    float* new_emaw = new_cs + KK;                           // [K*D]

    char* ws = (char*)d_ws;
    float* dw           = (float*)(ws + 4352);               // 256 KB
    float* csq_half     = (float*)(ws + 274688);             // 4 KB
    float* smoothed_inv = (float*)(ws + 278784);             // 4 KB
    unsigned char* cbhl = (unsigned char*)(ws + 282880);     // 288 KB
    int2*  pairs        = (int2*)(ws + 577792);              // 2 MB
    // region reuse (lifetimes disjoint):
    //  - counts_parts (64x1024 int = 256 KB) aliases cbhl: cbhl dead after
    //    k_assign; k_count writes, k_mid transforms in place, k_scatter reads
    //  - loss_parts (64 KB) aliases pairs start: read by k_mid before
    //    k_scatter overwrites pairs
    int*   counts_parts = (int*)(ws + 282880);
    float* loss_parts   = (float*)(ws + 577792);

    k_prep   <<<KK * DD / 256, 256, 0, stream>>>(cb, cbhl, csq_half, dw);
    k_assign <<<NN / 128, 256, 0, stream>>>(x, cbhl, csq_half, idx_reg);
    k_refine <<<RBLK, 256, 0, stream>>>(x, cb, csq_half, idx_reg, quant,
                                        loss_parts);
    k_count  <<<CBLK, 256, 0, stream>>>(idx_reg, counts_parts);
    k_mid    <<<1, 1024, 0, stream>>>(counts_parts, ema_cs, loss_parts,
                                      new_cs, loss_out, smoothed_inv);
    k_scatter<<<CBLK, 256, 0, stream>>>(idx_reg, counts_parts, pairs);
    k_segsum <<<NN / 256, 256, 0, stream>>>(x, pairs, dw);
    k_final  <<<KK * DD / 256, 256, 0, stream>>>(dw, ema_w, smoothed_inv,
                                                 new_emaw, new_cb);
}

// Round 9
// 246.530 us; speedup vs baseline: 2.0976x; 1.0646x over previous
//
#include <hip/hip_runtime.h>

#define NN 262144
#define KK 1024
#define DD 64
#define DECAY 0.99f
#define ONE_MINUS_DECAY 0.01f
#define EPSF 1e-5f
#define COMMIT 0.25f

// padded bf16 codebook planes: 144B per code row (72 bf16, 64 used + 8 pad)
#define ROWB 144
// chunk = 64 codes, DOUBLE-BUFFERED: 2 x 18432B = 36864B LDS -> 4 blocks/CU
#define CHUNK_CODES 64
#define PLANE_BYTES (CHUNK_CODES * ROWB)       // 9216
#define CHUNK_BYTES (PLANE_BYTES * 2)          // 18432
#define NCHUNK (KK / CHUNK_CODES)              // 16
#define RBLK 16384                              // k_refine blocks (= NN*16/256)
#define CBLK 64                                 // count/scatter blocks
#define ROWS_PER_CBLK (NN / CBLK)               // 4096

typedef __bf16 bf16x8 __attribute__((ext_vector_type(8)));
typedef unsigned short ushort8 __attribute__((ext_vector_type(8)));
typedef float float4v __attribute__((ext_vector_type(4)));

__device__ inline unsigned short bf16rne(float f) {
    unsigned int u = __float_as_uint(f);
    u += 0x7fffu + ((u >> 16) & 1u);
    return (unsigned short)(u >> 16);
}

// async global->LDS, 16B per lane; LDS dest must be linear in lane order
__device__ inline void glds16(const void* g, void* l) {
    __builtin_amdgcn_global_load_lds(
        (const __attribute__((address_space(1))) unsigned int*)g,
        (__attribute__((address_space(3))) unsigned int*)l, 16, 0, 0);
}

// --- fused: split codebook into chunked padded bf16 hi/lo planes + 0.5||c||^2
//     + zero-init of dw
__global__ __launch_bounds__(256) void k_prep(const float* __restrict__ cb,
                                              unsigned char* __restrict__ cbhl,
                                              float* __restrict__ csq_half,
                                              float* __restrict__ dw) {
    int e = blockIdx.x * 256 + threadIdx.x;      // 0..65535 == KK*DD
    dw[e] = 0.f;
    int k = e >> 6, d = e & 63;
    int c = k >> 6, kl = k & 63;
    float f = cb[e];
    unsigned short h = bf16rne(f);
    float hf = __uint_as_float((unsigned int)h << 16);
    unsigned short l = bf16rne(f - hf);
    unsigned char* base = cbhl + (size_t)c * CHUNK_BYTES;
    *(unsigned short*)(base + kl * ROWB + d * 2) = h;
    *(unsigned short*)(base + PLANE_BYTES + kl * ROWB + d * 2) = l;
    float s = f * f;
#pragma unroll
    for (int off = 32; off > 0; off >>= 1) s += __shfl_down(s, off);
    if (d == 0) csq_half[k] = 0.5f * s;
}

// --- assignment core: split-bf16 MFMA, packed-uint top-2 ONLY ---------------
// wave = 32 rows (2 m-tiles x 16). Round-8 counters: VALUBusy 50 > MfmaUtil
// 37 -> issue-bound on VALU. Single 6-deep acc chain (round-4's two-acc
// split cost 1 v_add per dp = 25% of inner VALU; 2 interleaved mt chains +
// 4 blocks/CU cover the latency). 3 VALU per dp: and_or + med3 + min.
// Bias (0.5||x||^2 + 1) folded into acc init: acc >= 1, raw float bits
// monotone, low 10 bits carry the code.
__global__ __launch_bounds__(256, 4) void k_assign(
    const float* __restrict__ x,
    const unsigned char* __restrict__ cbhl, const float* __restrict__ csq_half,
    int* __restrict__ kkpack)
{
    __shared__ __align__(16) unsigned char ldsbuf[2][CHUNK_BYTES];

    const int tid  = threadIdx.x;
    const int lane = tid & 63;
    const int wave = tid >> 6;
    const int col  = lane & 15;
    const int quad = lane >> 4;
    const int rowbase = blockIdx.x * 128 + wave * 32;

    // ---- issue stage of chunk 0 first: hides under the x-fragment prologue
    {
        const unsigned char* src = cbhl;
#pragma unroll
        for (int i = 0; i < 4; ++i) {
            int off = (i * 256 + tid) * 16;
            glds16(src + off, &ldsbuf[0][off]);
        }
        if (tid < 128) {
            int off = 16384 + tid * 16;
            glds16(src + off, &ldsbuf[0][off]);
        }
    }

    // ---- negated split-bf16 A fragments (2 m-tiles x 2 k-halves) + bias
    bf16x8 nah[2][2], nal[2][2];
    float xsq1[8];      // [mt*4+r] = 0.5*||x_row||^2 + 1, row = mt*16+quad*4+r
    {
        float xsqm[2];
#pragma unroll
        for (int mt = 0; mt < 2; ++mt) {
            const float* xb = x + (size_t)(rowbase + mt * 16 + col) * DD + quad * 8;
            float s = 0.f;
#pragma unroll
            for (int kh = 0; kh < 2; ++kh) {
                float4 f0 = *(const float4*)(xb + kh * 32);
                float4 f1 = *(const float4*)(xb + kh * 32 + 4);
                s += f0.x * f0.x + f0.y * f0.y + f0.z * f0.z + f0.w * f0.w;
                s += f1.x * f1.x + f1.y * f1.y + f1.z * f1.z + f1.w * f1.w;
                float fv[8] = {f0.x, f0.y, f0.z, f0.w, f1.x, f1.y, f1.z, f1.w};
                ushort8 uh, ul;
#pragma unroll
                for (int j = 0; j < 8; ++j) {
                    float nf = -fv[j];
                    unsigned short h = bf16rne(nf);
                    float hf = __uint_as_float((unsigned int)h << 16);
                    uh[j] = h;
                    ul[j] = bf16rne(nf - hf);
                }
                nah[mt][kh] = __builtin_bit_cast(bf16x8, uh);
                nal[mt][kh] = __builtin_bit_cast(bf16x8, ul);
            }
            s += __shfl_xor(s, 16);
            s += __shfl_xor(s, 32);          // full row norm^2 at all quads
            xsqm[mt] = s;
        }
#pragma unroll
        for (int mt = 0; mt < 2; ++mt)
#pragma unroll
            for (int r = 0; r < 4; ++r)
                xsq1[mt * 4 + r] = 0.5f * __shfl(xsqm[mt], quad * 4 + r) + 1.0f;
    }

    // ---- packed top-2 (value-bits | code) per 8 rows/lane
    unsigned int best[8], sec[8];
#pragma unroll
    for (int j = 0; j < 8; ++j) { best[j] = 0xFFFFFFFFu; sec[j] = 0xFFFFFFFFu; }

    // chunk 0 staged + x fragments done -> buffer 0 visible to all
    asm volatile("s_waitcnt vmcnt(0) lgkmcnt(0)" ::: "memory");
    __builtin_amdgcn_s_barrier();

    for (int chunk = 0; chunk < NCHUNK; ++chunk) {
        const unsigned char* cbuf = ldsbuf[chunk & 1];
        if (chunk + 1 < NCHUNK) {               // issue next-chunk stage
            unsigned char* nbuf = ldsbuf[(chunk + 1) & 1];
            const unsigned char* src = cbhl + (size_t)(chunk + 1) * CHUNK_BYTES;
#pragma unroll
            for (int i = 0; i < 4; ++i) {
                int off = (i * 256 + tid) * 16;
                glds16(src + off, nbuf + off);
            }
            if (tid < 128) {
                int off = 16384 + tid * 16;
                glds16(src + off, nbuf + off);
            }
        }

        float csqv[4];                        // per-chunk csq preload (L1-hit)
#pragma unroll
        for (int ct = 0; ct < 4; ++ct)
            csqv[ct] = csq_half[chunk * CHUNK_CODES + ct * 16 + col];

#pragma unroll
        for (int ct = 0; ct < CHUNK_CODES / 16; ++ct) {        // 4 code-tiles
            const int code_local = ct * 16 + col;
            const unsigned int codeCol = chunk * CHUNK_CODES + code_local;
            const unsigned char* bp = cbuf + code_local * ROWB + quad * 16;
            bf16x8 bh0 = __builtin_bit_cast(bf16x8, *(const uint4*)(bp));
            bf16x8 bh1 = __builtin_bit_cast(bf16x8, *(const uint4*)(bp + 64));
            bf16x8 bl0 = __builtin_bit_cast(bf16x8, *(const uint4*)(bp + PLANE_BYTES));
            bf16x8 bl1 = __builtin_bit_cast(bf16x8, *(const uint4*)(bp + PLANE_BYTES + 64));
            float csq = csqv[ct];

#pragma unroll
            for (int mt = 0; mt < 2; ++mt) {
                // single acc, 6-deep chain; mt0/mt1 chains interleave for ILP
                float4v a = {csq + xsq1[mt * 4 + 0], csq + xsq1[mt * 4 + 1],
                             csq + xsq1[mt * 4 + 2], csq + xsq1[mt * 4 + 3]};
                __builtin_amdgcn_s_setprio(1);
                a = __builtin_amdgcn_mfma_f32_16x16x32_bf16(nah[mt][0], bh0, a, 0, 0, 0);
                a = __builtin_amdgcn_mfma_f32_16x16x32_bf16(nah[mt][1], bh1, a, 0, 0, 0);
                a = __builtin_amdgcn_mfma_f32_16x16x32_bf16(nah[mt][0], bl0, a, 0, 0, 0);
                a = __builtin_amdgcn_mfma_f32_16x16x32_bf16(nah[mt][1], bl1, a, 0, 0, 0);
                a = __builtin_amdgcn_mfma_f32_16x16x32_bf16(nal[mt][0], bh0, a, 0, 0, 0);
                a = __builtin_amdgcn_mfma_f32_16x16x32_bf16(nal[mt][1], bh1, a, 0, 0, 0);
                __builtin_amdgcn_s_setprio(0);
#pragma unroll
                for (int r = 0; r < 4; ++r) {
                    // a[r] >= 1 -> bits monotone; 3 VALU per dp total
                    unsigned int u = (__float_as_uint(a[r]) & 0xFFFFFC00u) | codeCol;
                    unsigned int j = mt * 4 + r;
                    unsigned int s2;
                    // sec' = min(sec, max(best_old, u)) == med3(best_old, u, sec)
                    // (invariant sec >= best)
                    asm("v_med3_u32 %0, %1, %2, %3"
                        : "=v"(s2) : "v"(best[j]), "v"(u), "v"(sec[j]));
                    sec[j] = s2;
                    best[j] = best[j] < u ? best[j] : u;
                }
            }
        }

        // wait own ds_reads landed + next-chunk DMA complete, then sync
        asm volatile("s_waitcnt vmcnt(0) lgkmcnt(0)" ::: "memory");
        __builtin_amdgcn_s_barrier();
    }

    // ---- merge top-2 across the 16 col-lanes (packed: pure min/max)
#pragma unroll
    for (int m = 1; m <= 8; m <<= 1) {
#pragma unroll
        for (int j = 0; j < 8; ++j) {
            unsigned int ob = __shfl_xor(best[j], m, 16);
            unsigned int os = __shfl_xor(sec[j],  m, 16);
            unsigned int hi = best[j] > ob ? best[j] : ob;
            best[j] = best[j] < ob ? best[j] : ob;
            unsigned int s2 = sec[j] < os ? sec[j] : os;
            sec[j] = s2 < hi ? s2 : hi;
        }
    }

    // ---- write packed (k1 | k2<<10) per row; k_refine re-ranks exactly
    if (col == 0) {
#pragma unroll
        for (int j = 0; j < 8; ++j) {
            int row_local = (j >> 2) * 16 + quad * 4 + (j & 3);
            kkpack[rowbase + row_local] =
                (int)((best[j] & 1023u) | ((sec[j] & 1023u) << 10));
        }
    }
}

// --- exact fp32 refinement: coalesced, ZERO global atomics ------------------
__global__ __launch_bounds__(256) void k_refine(
    const float* __restrict__ x, const float* __restrict__ cb,
    const float* __restrict__ csq_half, int* __restrict__ idx_io,
    float* __restrict__ quant, float* __restrict__ loss_parts)
{
    __shared__ float werr[4];
    const int tid  = threadIdx.x;
    const int lane = tid & 63;
    const int d16  = lane & 15;           // float4 slot within row
    const int e    = blockIdx.x * 256 + tid;
    const int row  = e >> 4;

    unsigned int kp = (unsigned int)idx_io[row];   // 16 lanes same addr: bcast
    int k1 = (int)(kp & 1023u), k2 = (int)((kp >> 10) & 1023u);

    float4 x4 = *(const float4*)(x + (size_t)row * DD + d16 * 4);
    float4 c1 = *(const float4*)(cb + (size_t)k1 * DD + d16 * 4);
    float4 c2 = *(const float4*)(cb + (size_t)k2 * DD + d16 * 4);

    float p1 = x4.x * c1.x + x4.y * c1.y + x4.z * c1.z + x4.w * c1.w;
    float p2 = x4.x * c2.x + x4.y * c2.y + x4.z * c2.z + x4.w * c2.w;
#pragma unroll
    for (int off = 1; off < 16; off <<= 1) {
        p1 += __shfl_xor(p1, off, 16);
        p2 += __shfl_xor(p2, off, 16);
    }
    float d1 = csq_half[k1] - p1;
    float d2 = csq_half[k2] - p2;
    bool pick1 = (d1 < d2) || (d1 == d2 && k1 < k2);
    int w = pick1 ? k1 : k2;
    float4 q = pick1 ? c1 : c2;

    *(float4*)(quant + (size_t)row * DD + d16 * 4) = q;

    float ex = q.x - x4.x, ey = q.y - x4.y, ez = q.z - x4.z, ew = q.w - x4.w;
    float err = ex * ex + ey * ey + ez * ez + ew * ew;
#pragma unroll
    for (int off = 32; off > 0; off >>= 1) err += __shfl_down(err, off);
    if (lane == 0) werr[tid >> 6] = err;
    __syncthreads();
    if (tid == 0)
        loss_parts[blockIdx.x] = werr[0] + werr[1] + werr[2] + werr[3];

    if (d16 == 0) idx_io[row] = w;       // plain store, no atomic
}

// --- per-block LDS histogram: 64 blocks x 1024 thr x 4096 rows --------------
__global__ __launch_bounds__(1024) void k_count(
    const int* __restrict__ idx, int* __restrict__ counts_parts)
{
    __shared__ int hist[KK];
    const int tid = threadIdx.x;
    const int b   = blockIdx.x;
    hist[tid] = 0;
    __syncthreads();
    const int base = b * ROWS_PER_CBLK;
#pragma unroll
    for (int i = 0; i < ROWS_PER_CBLK / 1024; ++i)
        atomicAdd(&hist[idx[base + tid + i * 1024]], 1);   // LDS atomic
    __syncthreads();
    counts_parts[b * KK + tid] = hist[tid];
}

// --- single block: counts-reduce, EMA, smoothed, scan, loss, scatter bases --
// Transforms counts_parts IN PLACE into per-block scatter base offsets.
__global__ __launch_bounds__(1024) void k_mid(
    int* __restrict__ counts_parts, const float* __restrict__ ema_cs,
    const float* __restrict__ loss_parts,
    float* __restrict__ new_cs, float* __restrict__ loss_out,
    float* __restrict__ smoothed_inv)
{
    int t = threadIdx.x; int lane = t & 63; int w = t >> 6;

    __shared__ float wsumf[16];
    __shared__ int wsumi[16];
    __shared__ float wlp[16];
    __shared__ float ntot_s;

    // loss_parts reduce: 16384 = 1024 x 16 coalesced
    float lp = 0.f;
#pragma unroll
    for (int i = 0; i < RBLK / 1024; ++i) lp += loss_parts[t + i * 1024];
#pragma unroll
    for (int off = 32; off > 0; off >>= 1) lp += __shfl_down(lp, off);
    if (lane == 0) wlp[w] = lp;

    // counts[t] = sum over 64 per-block partials (coalesced per iteration)
    int cnt = 0;
    for (int b = 0; b < CBLK; ++b) cnt += counts_parts[b * KK + t];
    float ncs = DECAY * ema_cs[t] + ONE_MINUS_DECAY * (float)cnt;

    float s = ncs;
#pragma unroll
    for (int off = 32; off > 0; off >>= 1) s += __shfl_down(s, off);
    if (lane == 0) wsumf[w] = s;

    int v = cnt;
#pragma unroll
    for (int off = 1; off < 64; off <<= 1) {
        int u = __shfl_up(v, off);
        if (lane >= off) v += u;
    }
    if (lane == 63) wsumi[w] = v;
    __syncthreads();
    if (t == 0) {
        float tt = 0.f, lt = 0.f;
        for (int i = 0; i < 16; ++i) { tt += wsumf[i]; lt += wlp[i]; }
        ntot_s = tt;
        loss_out[0] = COMMIT * lt / (float)(NN * DD);
    }
    if (w == 0 && lane < 16) {
        int u = wsumi[lane]; int vv = u;
#pragma unroll
        for (int off = 1; off < 16; off <<= 1) {
            int p = __shfl_up(vv, off, 16);
            if ((lane & 15) >= off) vv += p;
        }
        wsumi[lane] = vv - u;
    }
    __syncthreads();
    float n = ntot_s;

    float sm = (ncs + EPSF) / (n + (float)KK * EPSF) * n;
    new_cs[t] = ncs;
    smoothed_inv[t] = 1.0f / sm;

    // exclusive global offset of code t, then in-place transform of
    // counts_parts[b][t] -> scatter base for block b (column t exclusive
    // to thread t: no races)
    int run = wsumi[w] + v - cnt;
    for (int b = 0; b < CBLK; ++b) {
        int c = counts_parts[b * KK + t];
        counts_parts[b * KK + t] = run;
        run += c;
    }
}

// --- scatter via LDS cursors seeded from per-block bases: no global atomics -
__global__ __launch_bounds__(1024) void k_scatter(
    int* __restrict__ idx_inout, const int* __restrict__ base_parts,
    int2* __restrict__ pairs)
{
    __shared__ int cur[KK];
    const int tid = threadIdx.x;
    const int b   = blockIdx.x;
    cur[tid] = base_parts[b * KK + tid];
    __syncthreads();
    const int base = b * ROWS_PER_CBLK;
#pragma unroll
    for (int i = 0; i < ROWS_PER_CBLK / 1024; ++i) {
        int r = base + tid + i * 1024;
        int k = idx_inout[r];
        int pos = atomicAdd(&cur[k], 1);             // LDS atomic
        pairs[pos] = make_int2(r, k);
        ((float*)idx_inout)[r] = (float)k;           // final float output
    }
}

// --- balanced segment sum: each wave 64 sorted rows, shfl-broadcast keys ----
// batched 8-wide: 8 independent gathers issued per group so HBM/L2 latency
// is exposed once per 8 rows instead of per row
__global__ __launch_bounds__(256) void k_segsum(
    const float* __restrict__ x, const int2* __restrict__ pairs,
    float* __restrict__ dw)
{
    int w = blockIdx.x * 4 + (threadIdx.x >> 6);   // 4096 waves total
    int lane = threadIdx.x & 63;
    int base = w * 64;
    int2 mine = pairs[base + lane];                // coalesced 512B per wave
    float acc = 0.f;
    int cur = __shfl(mine.y, 0);
    for (int rb = 0; rb < 64; rb += 8) {
        float v[8];
        int codes[8];
#pragma unroll
        for (int j = 0; j < 8; ++j) {
            int row  = __shfl(mine.x, rb + j);
            codes[j] = __shfl(mine.y, rb + j);
            v[j] = x[(size_t)row * DD + lane];     // 256B coalesced gather
        }
#pragma unroll
        for (int j = 0; j < 8; ++j) {
            if (codes[j] != cur) {                 // wave-uniform, rare
                atomicAdd(&dw[cur * DD + lane], acc);
                acc = 0.f; cur = codes[j];
            }
            acc += v[j];
        }
    }
    atomicAdd(&dw[cur * DD + lane], acc);
}

// --- EMA weight update + codebook normalize --------------------------------
__global__ __launch_bounds__(256) void k_final(
    const float* __restrict__ dw, const float* __restrict__ ema_w,
    const float* __restrict__ smoothed_inv,
    float* __restrict__ new_ema_w, float* __restrict__ new_cb)
{
    int i = blockIdx.x * 256 + threadIdx.x;
    int k = i >> 6;
    float nw = DECAY * ema_w[i] + ONE_MINUS_DECAY * dw[i];
    new_ema_w[i] = nw;
    new_cb[i] = nw * smoothed_inv[k];
}

extern "C" void kernel_launch(void* const* d_in, const int* in_sizes, int n_in,
                              void* d_out, int out_size, void* d_ws, size_t ws_size,
                              hipStream_t stream)
{
    const float* x      = (const float*)d_in[0];
    const float* cb     = (const float*)d_in[1];
    const float* ema_cs = (const float*)d_in[2];
    const float* ema_w  = (const float*)d_in[3];

    float* out      = (float*)d_out;
    float* quant    = out;                                   // [N*D]
    float* loss_out = out + (size_t)NN * DD;                 // [1]
    int*   idx_reg  = (int*)(out + (size_t)NN * DD + 1);     // [N] (float slot)
    float* new_cb   = out + (size_t)NN * DD + 1 + NN;        // [K*D]
    float* new_cs   = new_cb + (size_t)KK * DD;              // [K]
    float* new_emaw = new_cs + KK;                           // [K*D]

    char* ws = (char*)d_ws;
    float* dw           = (float*)(ws + 4352);               // 256 KB
    float* csq_half     = (float*)(ws + 274688);             // 4 KB
    float* smoothed_inv = (float*)(ws + 278784);             // 4 KB
    unsigned char* cbhl = (unsigned char*)(ws + 282880);     // 288 KB
    int2*  pairs        = (int2*)(ws + 577792);              // 2 MB
    // region reuse (lifetimes disjoint):
    //  - counts_parts (64x1024 int = 256 KB) aliases cbhl: cbhl dead after
    //    k_assign; k_count writes, k_mid transforms in place, k_scatter reads
    //  - loss_parts (64 KB) aliases pairs start: read by k_mid before
    //    k_scatter overwrites pairs
    int*   counts_parts = (int*)(ws + 282880);
    float* loss_parts   = (float*)(ws + 577792);

    k_prep   <<<KK * DD / 256, 256, 0, stream>>>(cb, cbhl, csq_half, dw);
    k_assign <<<NN / 128, 256, 0, stream>>>(x, cbhl, csq_half, idx_reg);
    k_refine <<<RBLK, 256, 0, stream>>>(x, cb, csq_half, idx_reg, quant,
                                        loss_parts);
    k_count  <<<CBLK, 1024, 0, stream>>>(idx_reg, counts_parts);
    k_mid    <<<1, 1024, 0, stream>>>(counts_parts, ema_cs, loss_parts,
                                      new_cs, loss_out, smoothed_inv);
    k_scatter<<<CBLK, 1024, 0, stream>>>(idx_reg, counts_parts, pairs);
    k_segsum <<<NN / 256, 256, 0, stream>>>(x, pairs, dw);
    k_final  <<<KK * DD / 256, 256, 0, stream>>>(dw, ema_w, smoothed_inv,
                                                 new_emaw, new_cb);
}